// Round 1
// baseline (890.266 us; speedup 1.0000x reference)
//
#include <hip/hip_runtime.h>

#define NODES 100000
#define NEDGE 1600000
#define INC 128
#define CC 32
#define HH 4
#define NEG 0.2f

// K1: h = x @ W  [N,128], plus a_src[n,h] = sum_c h*att_src, a_dst likewise.
// Block 256 = 128 cols x 2 node-subgroups; 8 nodes per block-iteration.
__global__ __launch_bounds__(256) void k_proj(const float* __restrict__ x,
        const float* __restrict__ W, const float* __restrict__ att_src,
        const float* __restrict__ att_dst, float* __restrict__ h,
        float* __restrict__ a_src, float* __restrict__ a_dst) {
    __shared__ float Ws[INC * 128];      // 64 KB
    __shared__ float xs[8][INC];         // 4 KB
    __shared__ float atts[128], attd[128];
    const int tid = threadIdx.x;
    for (int i = tid; i < INC * 128; i += 256) Ws[i] = W[i];
    if (tid < 128) { atts[tid] = att_src[tid]; attd[tid] = att_dst[tid]; }
    const int j = tid & 127;    // output column
    const int sub = tid >> 7;   // 0/1: which 4-node group

    for (int n0 = blockIdx.x * 8; n0 < NODES; n0 += gridDim.x * 8) {
        __syncthreads();  // protect xs from previous iter readers (also covers Ws init)
        for (int i = tid; i < 8 * INC; i += 256) {
            int nn = n0 + (i >> 7);
            if (nn < NODES) xs[i >> 7][i & 127] = x[(size_t)nn * INC + (i & 127)];
        }
        __syncthreads();
        float acc[4] = {0.f, 0.f, 0.f, 0.f};
        for (int k = 0; k < INC; ++k) {
            float w = Ws[k * 128 + j];   // 2-way bank alias across wave64: free
            #pragma unroll
            for (int r = 0; r < 4; ++r)
                acc[r] = fmaf(xs[sub * 4 + r][k], w, acc[r]);  // xs: broadcast
        }
        #pragma unroll
        for (int r = 0; r < 4; ++r) {
            int n = n0 + sub * 4 + r;
            if (n < NODES) {
                h[(size_t)n * INC + j] = acc[r];
                float vs = acc[r] * atts[j];
                float vd = acc[r] * attd[j];
                // reduce over c = j&31 within each aligned 32-lane group
                #pragma unroll
                for (int off = 16; off; off >>= 1) {
                    vs += __shfl_down(vs, off, 32);
                    vd += __shfl_down(vd, off, 32);
                }
                if ((j & 31) == 0) {
                    int head = j >> 5;
                    a_src[n * HH + head] = vs;
                    a_dst[n * HH + head] = vd;
                }
            }
        }
    }
}

// K2: per-edge exp(leaky(logit)) accumulated into denom[dst][h].
// No max-subtraction needed: logits are O(10), exp safe in fp32; alpha is
// invariant to the shift (1e-16 epsilon negligible vs denom >= exp(self-loop)).
__global__ void k_denom(const int* __restrict__ ei, const float* __restrict__ a_src,
        const float* __restrict__ a_dst, float* __restrict__ denom) {
    int e = blockIdx.x * blockDim.x + threadIdx.x;
    const int ET = NEDGE + NODES;
    if (e >= ET) return;
    int s, d;
    if (e < NEDGE) { s = ei[e]; d = ei[NEDGE + e]; } else { s = d = e - NEDGE; }
    #pragma unroll
    for (int hh = 0; hh < HH; ++hh) {
        float v = a_src[s * HH + hh] + a_dst[d * HH + hh];
        v = v > 0.f ? v : NEG * v;
        atomicAdd(&denom[d * HH + hh], __expf(v));
    }
}

// K3: one wave64 per edge. Lane j reads h[src][j] and h[src][64+j] (coalesced),
// weights by its two heads' alpha, folds the remaining head pair via
// shfl_xor(32), and lanes 0..31 emit one atomicAdd each into acc[dst][c]
// (head-mean folded in as *0.25).
__global__ __launch_bounds__(256) void k_scatter(const int* __restrict__ ei,
        const float* __restrict__ a_src, const float* __restrict__ a_dst,
        const float* __restrict__ denom, const float* __restrict__ h,
        float* __restrict__ acc) {
    long long gt = (long long)blockIdx.x * blockDim.x + threadIdx.x;
    int e = (int)(gt >> 6);
    int lane = (int)(gt & 63);
    const int ET = NEDGE + NODES;
    if (e >= ET) return;
    int s, d;
    if (e < NEDGE) { s = ei[e]; d = ei[NEDGE + e]; } else { s = d = e - NEDGE; }
    int h0 = lane >> 5;  // head of element j = lane (0 or 1)

    float v0 = a_src[s * HH + h0] + a_dst[d * HH + h0];
    v0 = v0 > 0.f ? v0 : NEG * v0;
    float al0 = __expf(v0) / (denom[d * HH + h0] + 1e-16f);

    float v2 = a_src[s * HH + h0 + 2] + a_dst[d * HH + h0 + 2];
    v2 = v2 > 0.f ? v2 : NEG * v2;
    float al2 = __expf(v2) / (denom[d * HH + h0 + 2] + 1e-16f);

    float val = al0 * h[(size_t)s * INC + lane]
              + al2 * h[(size_t)s * INC + 64 + lane];
    float tot = val + __shfl_xor(val, 32);  // fold heads {h0, h0+2} with {h0^1, (h0^1)+2}
    if (lane < 32) atomicAdd(&acc[(size_t)d * CC + lane], 0.25f * tot);
}

// K4: out = relu(acc + bias)
__global__ void k_final(const float* __restrict__ acc, const float* __restrict__ bias,
        float* __restrict__ out) {
    int i = blockIdx.x * blockDim.x + threadIdx.x;
    if (i >= NODES * CC) return;
    float v = acc[i] + bias[i & (CC - 1)];
    out[i] = v > 0.f ? v : 0.f;
}

extern "C" void kernel_launch(void* const* d_in, const int* in_sizes, int n_in,
                              void* d_out, int out_size, void* d_ws, size_t ws_size,
                              hipStream_t stream) {
    const float* x       = (const float*)d_in[0];
    const int*   ei      = (const int*)d_in[1];
    const float* W       = (const float*)d_in[2];
    const float* att_src = (const float*)d_in[3];
    const float* att_dst = (const float*)d_in[4];
    const float* bias    = (const float*)d_in[5];
    float* out = (float*)d_out;

    float* ws     = (float*)d_ws;
    float* h      = ws;                               // N*128
    float* a_src  = h + (size_t)NODES * INC;          // N*4
    float* a_dst  = a_src + (size_t)NODES * HH;       // N*4
    float* denom  = a_dst + (size_t)NODES * HH;       // N*4
    float* acc    = denom + (size_t)NODES * HH;       // N*32
    // denom and acc are contiguous: zero both in one memset (ws is 0xAA-poisoned)
    hipMemsetAsync(denom, 0, sizeof(float) * (size_t)NODES * (HH + CC), stream);

    k_proj<<<512, 256, 0, stream>>>(x, W, att_src, att_dst, h, a_src, a_dst);

    const int ET = NEDGE + NODES;
    k_denom<<<(ET + 255) / 256, 256, 0, stream>>>(ei, a_src, a_dst, denom);

    long long t3 = (long long)ET * 64;
    k_scatter<<<(int)((t3 + 255) / 256), 256, 0, stream>>>(ei, a_src, a_dst, denom, h, acc);

    k_final<<<(NODES * CC + 255) / 256, 256, 0, stream>>>(acc, bias, out);
}

// Round 2
// 470.891 us; speedup vs baseline: 1.8906x; 1.8906x over previous
//
#include <hip/hip_runtime.h>

#define NODES 100000
#define NEDGE 1600000
#define ET (NEDGE + NODES)
#define INC 128
#define CC 32
#define HH 4
#define NEG 0.2f
#define PB 32   // nodes per block-iteration in k_proj (100000 % 32 == 0)

// K1: h = x @ W  [N,128] + fused a_src/a_dst reductions.
// Block 256 = 32 col-groups (4 cols each) x 8 node-groups (4 nodes each).
// Inner loop: 8 ds_read_b128 per 64 FMA instructions -> VALU-bound.
__global__ __launch_bounds__(256) void k_proj(const float* __restrict__ x,
        const float* __restrict__ W, const float* __restrict__ att_src,
        const float* __restrict__ att_dst, float* __restrict__ h,
        float* __restrict__ a_src, float* __restrict__ a_dst) {
    __shared__ float Ws[INC * 128];   // [k][j], 64 KB
    __shared__ float xs[PB][INC];     // 16 KB
    const int tid = threadIdx.x;
    const int tx = tid & 31;          // cols [tx*4, tx*4+4)
    const int ty = tid >> 5;          // nodes [ty*4, ty*4+4)

    for (int i = tid * 4; i < INC * 128; i += 1024)
        *(float4*)(Ws + i) = *(const float4*)(W + i);

    const float4 as4 = *(const float4*)(att_src + tx * 4);
    const float4 ad4 = *(const float4*)(att_dst + tx * 4);

    for (int n0 = blockIdx.x * PB; n0 < NODES; n0 += gridDim.x * PB) {
        __syncthreads();   // also covers Ws init on first iter
        for (int i = tid; i < PB * 32; i += 256) {
            int nn = n0 + (i >> 5);
            *(float4*)(&xs[i >> 5][(i & 31) * 4]) =
                *(const float4*)(x + (size_t)nn * INC + (i & 31) * 4);
        }
        __syncthreads();

        float acc[4][4] = {};
        for (int k = 0; k < INC; k += 4) {
            float4 wv[4];
            #pragma unroll
            for (int kk = 0; kk < 4; ++kk)
                wv[kk] = *(float4*)(Ws + (k + kk) * 128 + tx * 4);
            #pragma unroll
            for (int r = 0; r < 4; ++r) {
                float4 xv = *(float4*)(&xs[ty * 4 + r][k]);
                const float xa[4] = {xv.x, xv.y, xv.z, xv.w};
                #pragma unroll
                for (int kk = 0; kk < 4; ++kk) {
                    acc[r][0] = fmaf(xa[kk], wv[kk].x, acc[r][0]);
                    acc[r][1] = fmaf(xa[kk], wv[kk].y, acc[r][1]);
                    acc[r][2] = fmaf(xa[kk], wv[kk].z, acc[r][2]);
                    acc[r][3] = fmaf(xa[kk], wv[kk].w, acc[r][3]);
                }
            }
        }

        #pragma unroll
        for (int r = 0; r < 4; ++r) {
            int n = n0 + ty * 4 + r;
            *(float4*)(h + (size_t)n * INC + tx * 4) =
                make_float4(acc[r][0], acc[r][1], acc[r][2], acc[r][3]);
            float ps = acc[r][0] * as4.x + acc[r][1] * as4.y
                     + acc[r][2] * as4.z + acc[r][3] * as4.w;
            float pd = acc[r][0] * ad4.x + acc[r][1] * ad4.y
                     + acc[r][2] * ad4.z + acc[r][3] * ad4.w;
            // reduce the 8 col-groups of each head (lanes tx&7) — width-8 shfl
            ps += __shfl_down(ps, 4, 8); ps += __shfl_down(ps, 2, 8); ps += __shfl_down(ps, 1, 8);
            pd += __shfl_down(pd, 4, 8); pd += __shfl_down(pd, 2, 8); pd += __shfl_down(pd, 1, 8);
            if ((tx & 7) == 0) {
                int hd = tx >> 3;
                a_src[n * HH + hd] = ps;
                a_dst[n * HH + hd] = pd;
            }
        }
    }
}

// K2: thread-per-(edge,head). 4 consecutive lanes -> 4 consecutive denom
// dwords -> ONE coalesced 16B atomic transaction per edge (was 4 scalar ones).
__global__ void k_denom(const int* __restrict__ ei, const float* __restrict__ a_src,
        const float* __restrict__ a_dst, float* __restrict__ denom) {
    int idx = blockIdx.x * blockDim.x + threadIdx.x;
    if (idx >= ET * HH) return;
    int e = idx >> 2, hh = idx & 3;
    int s, d;
    if (e < NEDGE) { s = ei[e]; d = ei[NEDGE + e]; } else { s = d = e - NEDGE; }
    float v = a_src[s * HH + hh] + a_dst[d * HH + hh];
    v = v > 0.f ? v : NEG * v;
    atomicAdd(&denom[d * HH + hh], __expf(v));
}

// K3: 32 lanes per edge (2 edges per wave). Lanes 0-3 of each half compute the
// 4 head alphas once (1 exp + 1 div instr per wave instead of 4); broadcast via
// shfl; each lane combines all 4 heads in-register (col = lane for every head)
// and issues one fully-coalesced 32-dword atomic per edge.
__global__ __launch_bounds__(256) void k_scatter(const int* __restrict__ ei,
        const float* __restrict__ a_src, const float* __restrict__ a_dst,
        const float* __restrict__ denom, const float* __restrict__ h,
        float* __restrict__ acc) {
    int gt = blockIdx.x * 256 + threadIdx.x;
    int e = gt >> 5;
    int l = threadIdx.x & 31;
    if (e >= ET) return;
    int s, d;
    if (e < NEDGE) { s = ei[e]; d = ei[NEDGE + e]; } else { s = d = e - NEDGE; }

    float al = 0.f;
    if (l < 4) {
        float v = a_src[s * HH + l] + a_dst[d * HH + l];
        v = v > 0.f ? v : NEG * v;
        al = __expf(v) / (denom[d * HH + l] + 1e-16f);
    }
    const int base = threadIdx.x & 32;  // wave-lane base of this edge's half
    float al0 = __shfl(al, base + 0, 64);
    float al1 = __shfl(al, base + 1, 64);
    float al2 = __shfl(al, base + 2, 64);
    float al3 = __shfl(al, base + 3, 64);

    const float* hp = h + (size_t)s * INC + l;
    float v = al0 * hp[0] + al1 * hp[32] + al2 * hp[64] + al3 * hp[96];
    atomicAdd(&acc[(size_t)d * CC + l], 0.25f * v);
}

// K4: out = relu(acc + bias)
__global__ void k_final(const float* __restrict__ acc, const float* __restrict__ bias,
        float* __restrict__ out) {
    int i = blockIdx.x * blockDim.x + threadIdx.x;
    if (i >= NODES * CC) return;
    float v = acc[i] + bias[i & (CC - 1)];
    out[i] = v > 0.f ? v : 0.f;
}

extern "C" void kernel_launch(void* const* d_in, const int* in_sizes, int n_in,
                              void* d_out, int out_size, void* d_ws, size_t ws_size,
                              hipStream_t stream) {
    const float* x       = (const float*)d_in[0];
    const int*   ei      = (const int*)d_in[1];
    const float* W       = (const float*)d_in[2];
    const float* att_src = (const float*)d_in[3];
    const float* att_dst = (const float*)d_in[4];
    const float* bias    = (const float*)d_in[5];
    float* out = (float*)d_out;

    float* ws     = (float*)d_ws;
    float* h      = ws;                               // N*128
    float* a_src  = h + (size_t)NODES * INC;          // N*4
    float* a_dst  = a_src + (size_t)NODES * HH;       // N*4
    float* denom  = a_dst + (size_t)NODES * HH;       // N*4
    float* acc    = denom + (size_t)NODES * HH;       // N*32
    hipMemsetAsync(denom, 0, sizeof(float) * (size_t)NODES * (HH + CC), stream);

    k_proj<<<625, 256, 0, stream>>>(x, W, att_src, att_dst, h, a_src, a_dst);

    k_denom<<<(ET * HH + 255) / 256, 256, 0, stream>>>(ei, a_src, a_dst, denom);

    long long t3 = (long long)ET * 32;
    k_scatter<<<(int)((t3 + 255) / 256), 256, 0, stream>>>(ei, a_src, a_dst, denom, h, acc);

    k_final<<<(NODES * CC + 255) / 256, 256, 0, stream>>>(acc, bias, out);
}

// Round 3
// 464.868 us; speedup vs baseline: 1.9151x; 1.0130x over previous
//
#include <hip/hip_runtime.h>

#define NODES 100000
#define NEDGE 1600000
#define ET (NEDGE + NODES)
#define INC 128
#define CC 32
#define HH 4
#define NEG 0.2f
#define PB 32   // nodes per block-iteration in k_proj (100000 % 32 == 0)

// round-to-nearest-even f32 -> bf16 bits
static __device__ inline unsigned short f2bf(float f) {
    unsigned u = __float_as_uint(f);
    u += 0x7FFFu + ((u >> 16) & 1u);
    return (unsigned short)(u >> 16);
}
static __device__ inline float bf2f(unsigned short s) {
    return __uint_as_float((unsigned)s << 16);
}

// K1: h = x @ W  [N,128] + fused a_src/a_dst reductions.
// Epilogue stores h as bf16 in head-transposed layout hb[n][c*4+h]
// (c=0..31, h=0..3) so the scatter reads all 4 heads of a column in one
// 8-byte load.
__global__ __launch_bounds__(256) void k_proj(const float* __restrict__ x,
        const float* __restrict__ W, const float* __restrict__ att_src,
        const float* __restrict__ att_dst, unsigned short* __restrict__ hb,
        float* __restrict__ a_src, float* __restrict__ a_dst) {
    __shared__ float Ws[INC * 128];   // [k][j], 64 KB
    __shared__ float xs[PB][INC];     // 16 KB, reused as output-tile staging
    const int tid = threadIdx.x;
    const int tx = tid & 31;          // cols [tx*4, tx*4+4)
    const int ty = tid >> 5;          // nodes [ty*4, ty*4+4)

    for (int i = tid * 4; i < INC * 128; i += 1024)
        *(float4*)(Ws + i) = *(const float4*)(W + i);

    const float4 as4 = *(const float4*)(att_src + tx * 4);
    const float4 ad4 = *(const float4*)(att_dst + tx * 4);

    for (int n0 = blockIdx.x * PB; n0 < NODES; n0 += gridDim.x * PB) {
        __syncthreads();   // also covers Ws init on first iter
        for (int i = tid; i < PB * 32; i += 256) {
            int nn = n0 + (i >> 5);
            *(float4*)(&xs[i >> 5][(i & 31) * 4]) =
                *(const float4*)(x + (size_t)nn * INC + (i & 31) * 4);
        }
        __syncthreads();

        float acc[4][4] = {};
        for (int k = 0; k < INC; k += 4) {
            float4 wv[4];
            #pragma unroll
            for (int kk = 0; kk < 4; ++kk)
                wv[kk] = *(float4*)(Ws + (k + kk) * 128 + tx * 4);
            #pragma unroll
            for (int r = 0; r < 4; ++r) {
                float4 xv = *(float4*)(&xs[ty * 4 + r][k]);
                const float xa[4] = {xv.x, xv.y, xv.z, xv.w};
                #pragma unroll
                for (int kk = 0; kk < 4; ++kk) {
                    acc[r][0] = fmaf(xa[kk], wv[kk].x, acc[r][0]);
                    acc[r][1] = fmaf(xa[kk], wv[kk].y, acc[r][1]);
                    acc[r][2] = fmaf(xa[kk], wv[kk].z, acc[r][2]);
                    acc[r][3] = fmaf(xa[kk], wv[kk].w, acc[r][3]);
                }
            }
        }

        // a_src / a_dst (fp32, pre-rounding)
        #pragma unroll
        for (int r = 0; r < 4; ++r) {
            int n = n0 + ty * 4 + r;
            float ps = acc[r][0] * as4.x + acc[r][1] * as4.y
                     + acc[r][2] * as4.z + acc[r][3] * as4.w;
            float pd = acc[r][0] * ad4.x + acc[r][1] * ad4.y
                     + acc[r][2] * ad4.z + acc[r][3] * ad4.w;
            ps += __shfl_down(ps, 4, 8); ps += __shfl_down(ps, 2, 8); ps += __shfl_down(ps, 1, 8);
            pd += __shfl_down(pd, 4, 8); pd += __shfl_down(pd, 2, 8); pd += __shfl_down(pd, 1, 8);
            if ((tx & 7) == 0) {
                int hd = tx >> 3;
                a_src[n * HH + hd] = ps;
                a_dst[n * HH + hd] = pd;
            }
        }

        // h tile -> LDS -> transposed bf16 store
        __syncthreads();   // xs readers of this iter are done
        #pragma unroll
        for (int r = 0; r < 4; ++r)
            *(float4*)(&xs[ty * 4 + r][tx * 4]) =
                make_float4(acc[r][0], acc[r][1], acc[r][2], acc[r][3]);
        __syncthreads();
        for (int item = tid; item < PB * 32; item += 256) {
            int nl = item >> 5, c = item & 31;   // bank = c: conflict-free
            ushort4 pk;
            pk.x = f2bf(xs[nl][c]);
            pk.y = f2bf(xs[nl][32 + c]);
            pk.z = f2bf(xs[nl][64 + c]);
            pk.w = f2bf(xs[nl][96 + c]);
            *(ushort4*)(hb + (size_t)(n0 + nl) * INC + c * 4) = pk;  // 8B coalesced
        }
    }
}

// K2: thread-per-(edge,head); 4 consecutive lanes -> one coalesced 16B atomic.
__global__ void k_denom(const int* __restrict__ ei, const float* __restrict__ a_src,
        const float* __restrict__ a_dst, float* __restrict__ denom) {
    int idx = blockIdx.x * blockDim.x + threadIdx.x;
    if (idx >= ET * HH) return;
    int e = idx >> 2, hh = idx & 3;
    int s, d;
    if (e < NEDGE) { s = ei[e]; d = ei[NEDGE + e]; } else { s = d = e - NEDGE; }
    float v = a_src[s * HH + hh] + a_dst[d * HH + hh];
    v = v > 0.f ? v : NEG * v;
    atomicAdd(&denom[d * HH + hh], __expf(v));
}

// K3: 32 lanes per edge. Lanes 0-3 of each half compute the 4 head alphas,
// broadcast via shfl. Lane l loads all 4 heads of column l as one 8B ushort4
// (bf16), combines, and issues one fully-coalesced 32-dword atomic per edge.
__global__ __launch_bounds__(256) void k_scatter(const int* __restrict__ ei,
        const float* __restrict__ a_src, const float* __restrict__ a_dst,
        const float* __restrict__ denom, const unsigned short* __restrict__ hb,
        float* __restrict__ acc) {
    int gt = blockIdx.x * 256 + threadIdx.x;
    int e = gt >> 5;
    int l = threadIdx.x & 31;
    if (e >= ET) return;
    int s, d;
    if (e < NEDGE) { s = ei[e]; d = ei[NEDGE + e]; } else { s = d = e - NEDGE; }

    float al = 0.f;
    if (l < 4) {
        float v = a_src[s * HH + l] + a_dst[d * HH + l];
        v = v > 0.f ? v : NEG * v;
        al = __expf(v) / (denom[d * HH + l] + 1e-16f);
    }
    const int base = threadIdx.x & 32;  // wave-lane base of this edge's half
    float al0 = __shfl(al, base + 0, 64);
    float al1 = __shfl(al, base + 1, 64);
    float al2 = __shfl(al, base + 2, 64);
    float al3 = __shfl(al, base + 3, 64);

    ushort4 hv = *(const ushort4*)(hb + (size_t)s * INC + l * 4);
    float v = al0 * bf2f(hv.x) + al1 * bf2f(hv.y)
            + al2 * bf2f(hv.z) + al3 * bf2f(hv.w);
    atomicAdd(&acc[(size_t)d * CC + l], 0.25f * v);
}

// K4: out = relu(acc + bias)
__global__ void k_final(const float* __restrict__ acc, const float* __restrict__ bias,
        float* __restrict__ out) {
    int i = blockIdx.x * blockDim.x + threadIdx.x;
    if (i >= NODES * CC) return;
    float v = acc[i] + bias[i & (CC - 1)];
    out[i] = v > 0.f ? v : 0.f;
}

extern "C" void kernel_launch(void* const* d_in, const int* in_sizes, int n_in,
                              void* d_out, int out_size, void* d_ws, size_t ws_size,
                              hipStream_t stream) {
    const float* x       = (const float*)d_in[0];
    const int*   ei      = (const int*)d_in[1];
    const float* W       = (const float*)d_in[2];
    const float* att_src = (const float*)d_in[3];
    const float* att_dst = (const float*)d_in[4];
    const float* bias    = (const float*)d_in[5];
    float* out = (float*)d_out;

    unsigned short* hb = (unsigned short*)d_ws;              // N*128 bf16 = 25.6 MB
    float* fbase  = (float*)(hb + (size_t)NODES * INC);
    float* a_src  = fbase;                                   // N*4
    float* a_dst  = a_src + (size_t)NODES * HH;              // N*4
    float* denom  = a_dst + (size_t)NODES * HH;              // N*4
    float* acc    = denom + (size_t)NODES * HH;              // N*32
    hipMemsetAsync(denom, 0, sizeof(float) * (size_t)NODES * (HH + CC), stream);

    k_proj<<<625, 256, 0, stream>>>(x, W, att_src, att_dst, hb, a_src, a_dst);

    k_denom<<<(ET * HH + 255) / 256, 256, 0, stream>>>(ei, a_src, a_dst, denom);

    long long t3 = (long long)ET * 32;
    k_scatter<<<(int)((t3 + 255) / 256), 256, 0, stream>>>(ei, a_src, a_dst, denom, hb, acc);

    k_final<<<(NODES * CC + 255) / 256, 256, 0, stream>>>(acc, bias, out);
}

// Round 4
// 420.583 us; speedup vs baseline: 2.1167x; 1.1053x over previous
//
#include <hip/hip_runtime.h>

#define NODES 100000
#define NEDGE 1600000
#define ET (NEDGE + NODES)
#define INC 128
#define CC 32
#define HH 4
#define NEG 0.2f

typedef __attribute__((ext_vector_type(8))) short short8;   // 8 bf16 (4 VGPRs)
typedef __attribute__((ext_vector_type(4))) float f32x4;    // MFMA C/D

// round-to-nearest-even f32 -> bf16 bits
static __device__ inline unsigned short f2bf(float f) {
    unsigned u = __float_as_uint(f);
    u += 0x7FFFu + ((u >> 16) & 1u);
    return (unsigned short)(u >> 16);
}
static __device__ inline float bf2f(unsigned short s) {
    return __uint_as_float((unsigned)s << 16);
}

// K1: h = x @ W via bf16 MFMA (fp32 accumulate). Block = 4 waves = 64 rows.
// Wave w: rows [b*64+w*16, +16) x all 128 cols (8 col-tiles of 16).
// A-frag (16x16x32): A[m=lane&15][k=quad*8+j]  -> straight from global x.
// B-frag:            B[k=quad*8+j][n=lane&15]  -> Wt[col][k] bf16 LDS, pad 136.
// C/D:               row=quad*4+reg, col=lane&15.
// Epilogue: hb[n][c*4+head] bf16 store + a_src/a_dst via width-16 shfl_xor
// reductions of the fp32 accumulators (logit accuracy ~fp32).
__global__ __launch_bounds__(256) void k_proj(const float* __restrict__ x,
        const float* __restrict__ W, const float* __restrict__ att_src,
        const float* __restrict__ att_dst, unsigned short* __restrict__ hb,
        float* __restrict__ a_src, float* __restrict__ a_dst) {
    __shared__ unsigned short Wt[128][136];   // [col][k] bf16, 34.8 KB
    __shared__ float atts[128], attd[128];
    const int tid = threadIdx.x;

    for (int i = tid; i < 128 * 128; i += 256) {
        int k = i >> 7, c = i & 127;
        Wt[c][k] = f2bf(W[i]);
    }
    if (tid < 128) { atts[tid] = att_src[tid]; attd[tid] = att_dst[tid]; }
    __syncthreads();

    const int w    = tid >> 6;
    const int lane = tid & 63;
    const int quad = lane >> 4;
    const int l15  = lane & 15;

    // ---- A fragments: row = base + l15, k-window = kt*32 + quad*8 ----
    const int arow = blockIdx.x * 64 + w * 16 + l15;
    short8 af[4];
    if (arow < NODES) {
        const float* xp = x + (size_t)arow * INC + quad * 8;
        #pragma unroll
        for (int kt = 0; kt < 4; ++kt) {
            float4 u = *(const float4*)(xp + kt * 32);
            float4 v = *(const float4*)(xp + kt * 32 + 4);
            short8 a;
            a[0] = (short)f2bf(u.x); a[1] = (short)f2bf(u.y);
            a[2] = (short)f2bf(u.z); a[3] = (short)f2bf(u.w);
            a[4] = (short)f2bf(v.x); a[5] = (short)f2bf(v.y);
            a[6] = (short)f2bf(v.z); a[7] = (short)f2bf(v.w);
            af[kt] = a;
        }
    } else {
        #pragma unroll
        for (int kt = 0; kt < 4; ++kt) af[kt] = (short8){0,0,0,0,0,0,0,0};
    }

    const int orow = blockIdx.x * 64 + w * 16 + quad * 4;   // + reg
    float aps[4] = {0.f,0.f,0.f,0.f}, apd[4] = {0.f,0.f,0.f,0.f};

    for (int ct = 0; ct < 8; ++ct) {
        const int gcol = ct * 16 + l15;
        f32x4 acc = {0.f, 0.f, 0.f, 0.f};
        #pragma unroll
        for (int kt = 0; kt < 4; ++kt) {
            short8 bf = *(short8*)(&Wt[gcol][kt * 32 + quad * 8]);
            acc = __builtin_amdgcn_mfma_f32_16x16x32_bf16(af[kt], bf, acc, 0, 0, 0);
        }
        const float as = atts[gcol], ad = attd[gcol];
        const int head = ct >> 1;
        const int cidx = gcol & 31;
        #pragma unroll
        for (int reg = 0; reg < 4; ++reg) {
            float v = acc[reg];
            int r = orow + reg;
            if (r < NODES)
                hb[(size_t)r * INC + cidx * 4 + head] = f2bf(v);
            aps[reg] = fmaf(v, as, aps[reg]);
            apd[reg] = fmaf(v, ad, apd[reg]);
        }
        if (ct & 1) {   // head's 32 cols complete -> reduce + store a_src/a_dst
            #pragma unroll
            for (int reg = 0; reg < 4; ++reg) {
                float ps = aps[reg], pd = apd[reg];
                ps += __shfl_xor(ps, 1, 16); ps += __shfl_xor(ps, 2, 16);
                ps += __shfl_xor(ps, 4, 16); ps += __shfl_xor(ps, 8, 16);
                pd += __shfl_xor(pd, 1, 16); pd += __shfl_xor(pd, 2, 16);
                pd += __shfl_xor(pd, 4, 16); pd += __shfl_xor(pd, 8, 16);
                int r = orow + reg;
                if (l15 == 0 && r < NODES) {
                    a_src[r * HH + head] = ps;
                    a_dst[r * HH + head] = pd;
                }
                aps[reg] = 0.f; apd[reg] = 0.f;
            }
        }
    }
}

// K2: thread-per-(edge,head); 4 consecutive lanes -> one coalesced 16B atomic.
__global__ void k_denom(const int* __restrict__ ei, const float* __restrict__ a_src,
        const float* __restrict__ a_dst, float* __restrict__ denom) {
    int idx = blockIdx.x * blockDim.x + threadIdx.x;
    if (idx >= ET * HH) return;
    int e = idx >> 2, hh = idx & 3;
    int s, d;
    if (e < NEDGE) { s = ei[e]; d = ei[NEDGE + e]; } else { s = d = e - NEDGE; }
    float v = a_src[s * HH + hh] + a_dst[d * HH + hh];
    v = v > 0.f ? v : NEG * v;
    atomicAdd(&denom[d * HH + hh], __expf(v));
}

// K3: 32 lanes per edge. Lanes 0-3 of each half compute the 4 head alphas,
// broadcast via shfl. Lane l loads all 4 heads of column l as one 8B ushort4
// (bf16), combines, and issues one fully-coalesced 32-dword atomic per edge.
__global__ __launch_bounds__(256) void k_scatter(const int* __restrict__ ei,
        const float* __restrict__ a_src, const float* __restrict__ a_dst,
        const float* __restrict__ denom, const unsigned short* __restrict__ hb,
        float* __restrict__ acc) {
    int gt = blockIdx.x * 256 + threadIdx.x;
    int e = gt >> 5;
    int l = threadIdx.x & 31;
    if (e >= ET) return;
    int s, d;
    if (e < NEDGE) { s = ei[e]; d = ei[NEDGE + e]; } else { s = d = e - NEDGE; }

    float al = 0.f;
    if (l < 4) {
        float v = a_src[s * HH + l] + a_dst[d * HH + l];
        v = v > 0.f ? v : NEG * v;
        al = __expf(v) / (denom[d * HH + l] + 1e-16f);
    }
    const int base = threadIdx.x & 32;  // wave-lane base of this edge's half
    float al0 = __shfl(al, base + 0, 64);
    float al1 = __shfl(al, base + 1, 64);
    float al2 = __shfl(al, base + 2, 64);
    float al3 = __shfl(al, base + 3, 64);

    ushort4 hv = *(const ushort4*)(hb + (size_t)s * INC + l * 4);
    float v = al0 * bf2f(hv.x) + al1 * bf2f(hv.y)
            + al2 * bf2f(hv.z) + al3 * bf2f(hv.w);
    atomicAdd(&acc[(size_t)d * CC + l], 0.25f * v);
}

// K4: out = relu(acc + bias)
__global__ void k_final(const float* __restrict__ acc, const float* __restrict__ bias,
        float* __restrict__ out) {
    int i = blockIdx.x * blockDim.x + threadIdx.x;
    if (i >= NODES * CC) return;
    float v = acc[i] + bias[i & (CC - 1)];
    out[i] = v > 0.f ? v : 0.f;
}

extern "C" void kernel_launch(void* const* d_in, const int* in_sizes, int n_in,
                              void* d_out, int out_size, void* d_ws, size_t ws_size,
                              hipStream_t stream) {
    const float* x       = (const float*)d_in[0];
    const int*   ei      = (const int*)d_in[1];
    const float* W       = (const float*)d_in[2];
    const float* att_src = (const float*)d_in[3];
    const float* att_dst = (const float*)d_in[4];
    const float* bias    = (const float*)d_in[5];
    float* out = (float*)d_out;

    unsigned short* hb = (unsigned short*)d_ws;              // N*128 bf16 = 25.6 MB
    float* fbase  = (float*)(hb + (size_t)NODES * INC);
    float* a_src  = fbase;                                   // N*4
    float* a_dst  = a_src + (size_t)NODES * HH;              // N*4
    float* denom  = a_dst + (size_t)NODES * HH;              // N*4
    float* acc    = denom + (size_t)NODES * HH;              // N*32
    hipMemsetAsync(denom, 0, sizeof(float) * (size_t)NODES * (HH + CC), stream);

    k_proj<<<(NODES + 63) / 64, 256, 0, stream>>>(x, W, att_src, att_dst, hb, a_src, a_dst);

    k_denom<<<(ET * HH + 255) / 256, 256, 0, stream>>>(ei, a_src, a_dst, denom);

    long long t3 = (long long)ET * 32;
    k_scatter<<<(int)((t3 + 255) / 256), 256, 0, stream>>>(ei, a_src, a_dst, denom, hb, acc);

    k_final<<<(NODES * CC + 255) / 256, 256, 0, stream>>>(acc, bias, out);
}

// Round 5
// 418.058 us; speedup vs baseline: 2.1295x; 1.0060x over previous
//
#include <hip/hip_runtime.h>

#define NODES 100000
#define NEDGE 1600000
#define ET (NEDGE + NODES)
#define INC 128
#define CC 32
#define HH 4
#define NEG 0.2f

typedef __attribute__((ext_vector_type(8))) short short8;   // 8 bf16 (4 VGPRs)
typedef __attribute__((ext_vector_type(4))) float f32x4;    // MFMA C/D

// round-to-nearest-even f32 -> bf16 bits
static __device__ inline unsigned short f2bf(float f) {
    unsigned u = __float_as_uint(f);
    u += 0x7FFFu + ((u >> 16) & 1u);
    return (unsigned short)(u >> 16);
}
static __device__ inline float bf2f(unsigned short s) {
    return __uint_as_float((unsigned)s << 16);
}

// K1: h = x @ W via bf16 MFMA (fp32 accumulate). Block = 4 waves = 64 rows
// per stripe, 3 stripes per block (grid 521). Wt staged once per block.
// A-frag (16x16x32): A[m=lane&15][k=quad*8+j]  -> straight from global x.
// B-frag:            B[k=quad*8+j][n=lane&15]  -> Wt[col][k] bf16 LDS, pad 136.
// C/D:               row=quad*4+reg, col=lane&15.
// Epilogue: for fixed (lane,reg) the 4 heads of col l15 are accs[{0,2,4,6}][reg]
// and of col 16+l15 are accs[{1,3,5,7}][reg] -> pack ushort4 in-register,
// dense 8B stores (4x128B segments per instr). No LDS round-trip.
__global__ __launch_bounds__(256) void k_proj(const float* __restrict__ x,
        const float* __restrict__ W, const float* __restrict__ att_src,
        const float* __restrict__ att_dst, unsigned short* __restrict__ hb,
        float* __restrict__ a_src, float* __restrict__ a_dst) {
    __shared__ unsigned short Wt[128][136];   // [col][k] bf16, 34.8 KB
    __shared__ float atts[128], attd[128];
    const int tid = threadIdx.x;

    for (int i = tid; i < 128 * 128; i += 256) {
        int k = i >> 7, c = i & 127;
        Wt[c][k] = f2bf(W[i]);
    }
    if (tid < 128) { atts[tid] = att_src[tid]; attd[tid] = att_dst[tid]; }
    __syncthreads();

    const int w    = tid >> 6;
    const int lane = tid & 63;
    const int quad = lane >> 4;
    const int l15  = lane & 15;

    for (int base = blockIdx.x * 64; base < NODES; base += gridDim.x * 64) {
        // ---- A fragments: row = base + w*16 + l15, k-window = kt*32 + quad*8
        const int arow = base + w * 16 + l15;
        short8 af[4];
        if (arow < NODES) {
            const float* xp = x + (size_t)arow * INC + quad * 8;
            #pragma unroll
            for (int kt = 0; kt < 4; ++kt) {
                float4 u = *(const float4*)(xp + kt * 32);
                float4 v = *(const float4*)(xp + kt * 32 + 4);
                short8 a;
                a[0] = (short)f2bf(u.x); a[1] = (short)f2bf(u.y);
                a[2] = (short)f2bf(u.z); a[3] = (short)f2bf(u.w);
                a[4] = (short)f2bf(v.x); a[5] = (short)f2bf(v.y);
                a[6] = (short)f2bf(v.z); a[7] = (short)f2bf(v.w);
                af[kt] = a;
            }
        } else {
            #pragma unroll
            for (int kt = 0; kt < 4; ++kt) af[kt] = (short8){0,0,0,0,0,0,0,0};
        }

        f32x4 accs[8];
        #pragma unroll
        for (int ct = 0; ct < 8; ++ct) {
            const int gcol = ct * 16 + l15;
            f32x4 acc = {0.f, 0.f, 0.f, 0.f};
            #pragma unroll
            for (int kt = 0; kt < 4; ++kt) {
                short8 bf = *(short8*)(&Wt[gcol][kt * 32 + quad * 8]);
                acc = __builtin_amdgcn_mfma_f32_16x16x32_bf16(af[kt], bf, acc, 0, 0, 0);
            }
            accs[ct] = acc;
        }

        const int orow = base + w * 16 + quad * 4;   // + reg

        // ---- a_src / a_dst: per head, sum over 32 cols (fp32 accs) ----
        #pragma unroll
        for (int head = 0; head < HH; ++head) {
            const float asl = atts[head * 32 + l15], ash = atts[head * 32 + 16 + l15];
            const float adl = attd[head * 32 + l15], adh = attd[head * 32 + 16 + l15];
            #pragma unroll
            for (int reg = 0; reg < 4; ++reg) {
                float ps = accs[head * 2][reg] * asl + accs[head * 2 + 1][reg] * ash;
                float pd = accs[head * 2][reg] * adl + accs[head * 2 + 1][reg] * adh;
                ps += __shfl_xor(ps, 1, 16); ps += __shfl_xor(ps, 2, 16);
                ps += __shfl_xor(ps, 4, 16); ps += __shfl_xor(ps, 8, 16);
                pd += __shfl_xor(pd, 1, 16); pd += __shfl_xor(pd, 2, 16);
                pd += __shfl_xor(pd, 4, 16); pd += __shfl_xor(pd, 8, 16);
                int r = orow + reg;
                if (l15 == 0 && r < NODES) {
                    a_src[r * HH + head] = ps;
                    a_dst[r * HH + head] = pd;
                }
            }
        }

        // ---- hb[n][c*4+head] bf16, packed in-register ----
        #pragma unroll
        for (int reg = 0; reg < 4; ++reg) {
            int r = orow + reg;
            if (r < NODES) {
                ushort4 lo, hi;
                lo.x = f2bf(accs[0][reg]); lo.y = f2bf(accs[2][reg]);
                lo.z = f2bf(accs[4][reg]); lo.w = f2bf(accs[6][reg]);
                hi.x = f2bf(accs[1][reg]); hi.y = f2bf(accs[3][reg]);
                hi.z = f2bf(accs[5][reg]); hi.w = f2bf(accs[7][reg]);
                *(ushort4*)(hb + (size_t)r * INC + l15 * 4) = lo;
                *(ushort4*)(hb + (size_t)r * INC + (16 + l15) * 4) = hi;
            }
        }
    }
}

// K2: thread-per-(edge,head); 4 consecutive lanes -> one coalesced 16B atomic.
// Also caches p = exp(leaky(logit)) as bf16 for the scatter pass.
__global__ void k_denom(const int* __restrict__ ei, const float* __restrict__ a_src,
        const float* __restrict__ a_dst, float* __restrict__ denom,
        unsigned short* __restrict__ pe) {
    int idx = blockIdx.x * blockDim.x + threadIdx.x;
    if (idx >= ET * HH) return;
    int e = idx >> 2, hh = idx & 3;
    int s, d;
    if (e < NEDGE) { s = ei[e]; d = ei[NEDGE + e]; } else { s = d = e - NEDGE; }
    float v = a_src[s * HH + hh] + a_dst[d * HH + hh];
    v = v > 0.f ? v : NEG * v;
    float p = __expf(v);
    atomicAdd(&denom[d * HH + hh], p);
    pe[idx] = f2bf(p);
}

// K3: 32 lanes per edge. Lanes 0-3 read cached p (coalesced 2B) + denom
// (one random 16B), divide, broadcast via shfl. Lane l loads all 4 heads of
// column l as one 8B ushort4 (bf16) and issues one coalesced 32-dword atomic.
__global__ __launch_bounds__(256) void k_scatter(const int* __restrict__ ei,
        const unsigned short* __restrict__ pe, const float* __restrict__ denom,
        const unsigned short* __restrict__ hb, float* __restrict__ acc) {
    int gt = blockIdx.x * 256 + threadIdx.x;
    int e = gt >> 5;
    int l = threadIdx.x & 31;
    if (e >= ET) return;
    int s, d;
    if (e < NEDGE) { s = ei[e]; d = ei[NEDGE + e]; } else { s = d = e - NEDGE; }

    float al = 0.f;
    if (l < 4) {
        float p = bf2f(pe[e * 4 + l]);
        al = p / (denom[d * HH + l] + 1e-16f);
    }
    const int base = threadIdx.x & 32;  // wave-lane base of this edge's half
    float al0 = __shfl(al, base + 0, 64);
    float al1 = __shfl(al, base + 1, 64);
    float al2 = __shfl(al, base + 2, 64);
    float al3 = __shfl(al, base + 3, 64);

    ushort4 hv = *(const ushort4*)(hb + (size_t)s * INC + l * 4);
    float v = al0 * bf2f(hv.x) + al1 * bf2f(hv.y)
            + al2 * bf2f(hv.z) + al3 * bf2f(hv.w);
    atomicAdd(&acc[(size_t)d * CC + l], 0.25f * v);
}

// K4: out = relu(acc + bias)
__global__ void k_final(const float* __restrict__ acc, const float* __restrict__ bias,
        float* __restrict__ out) {
    int i = blockIdx.x * blockDim.x + threadIdx.x;
    if (i >= NODES * CC) return;
    float v = acc[i] + bias[i & (CC - 1)];
    out[i] = v > 0.f ? v : 0.f;
}

extern "C" void kernel_launch(void* const* d_in, const int* in_sizes, int n_in,
                              void* d_out, int out_size, void* d_ws, size_t ws_size,
                              hipStream_t stream) {
    const float* x       = (const float*)d_in[0];
    const int*   ei      = (const int*)d_in[1];
    const float* W       = (const float*)d_in[2];
    const float* att_src = (const float*)d_in[3];
    const float* att_dst = (const float*)d_in[4];
    const float* bias    = (const float*)d_in[5];
    float* out = (float*)d_out;

    unsigned short* hb = (unsigned short*)d_ws;              // N*128 bf16 = 25.6 MB
    unsigned short* pe = hb + (size_t)NODES * INC;           // ET*4 bf16 = 13.6 MB
    float* fbase  = (float*)(pe + (size_t)ET * HH);
    float* a_src  = fbase;                                   // N*4
    float* a_dst  = a_src + (size_t)NODES * HH;              // N*4
    float* denom  = a_dst + (size_t)NODES * HH;              // N*4
    float* acc    = denom + (size_t)NODES * HH;              // N*32
    hipMemsetAsync(denom, 0, sizeof(float) * (size_t)NODES * (HH + CC), stream);

    k_proj<<<521, 256, 0, stream>>>(x, W, att_src, att_dst, hb, a_src, a_dst);

    k_denom<<<(ET * HH + 255) / 256, 256, 0, stream>>>(ei, a_src, a_dst, denom, pe);

    long long t3 = (long long)ET * 32;
    k_scatter<<<(int)((t3 + 255) / 256), 256, 0, stream>>>(ei, pe, denom, hb, acc);

    k_final<<<(NODES * CC + 255) / 256, 256, 0, stream>>>(acc, bias, out);
}

// Round 7
// 323.108 us; speedup vs baseline: 2.7553x; 1.2939x over previous
//
#include <hip/hip_runtime.h>

#define NODES 100000
#define NEDGE 1600000
#define ET (NEDGE + NODES)
#define INC 128
#define CC 32
#define HH 4
#define NEG 0.2f

typedef __attribute__((ext_vector_type(8))) short short8;   // 8 bf16 (4 VGPRs)
typedef __attribute__((ext_vector_type(4))) float f32x4;    // MFMA C/D
typedef __attribute__((ext_vector_type(8))) unsigned short u16x8;
typedef _Float16 v2h __attribute__((ext_vector_type(2)));

// round-to-nearest-even f32 -> bf16 bits
static __device__ inline unsigned short f2bf(float f) {
    unsigned u = __float_as_uint(f);
    u += 0x7FFFu + ((u >> 16) & 1u);
    return (unsigned short)(u >> 16);
}
static __device__ inline float bf2f(unsigned short s) {
    return __uint_as_float((unsigned)s << 16);
}

// packed fp16 atomic add: ONE dword-atomic for two fp16 accumulators.
// fp16 (10 mantissa bits) keeps the running-sum rounding walk ~8x tighter
// than bf16 (which failed accuracy in round 6 at 3.1e-2).
static __device__ inline void pk_add_f16(unsigned short* addr, float a, float b) {
    v2h v; v[0] = (_Float16)a; v[1] = (_Float16)b;
#if __has_builtin(__builtin_amdgcn_flat_atomic_fadd_v2f16)
    __builtin_amdgcn_flat_atomic_fadd_v2f16((v2h*)(void*)addr, v);
#else
    __builtin_amdgcn_global_atomic_fadd_v2f16(
        (__attribute__((address_space(1))) v2h*)(void*)addr, v);
#endif
}

// K1: h = x @ W via bf16 MFMA (fp32 accumulate). Block = 4 waves = 64 rows
// per stripe, 3 stripes per block (grid 521). Wt staged once per block.
__global__ __launch_bounds__(256) void k_proj(const float* __restrict__ x,
        const float* __restrict__ W, const float* __restrict__ att_src,
        const float* __restrict__ att_dst, unsigned short* __restrict__ hb,
        float* __restrict__ a_src, float* __restrict__ a_dst) {
    __shared__ unsigned short Wt[128][136];   // [col][k] bf16, 34.8 KB
    __shared__ float atts[128], attd[128];
    const int tid = threadIdx.x;

    for (int i = tid; i < 128 * 128; i += 256) {
        int k = i >> 7, c = i & 127;
        Wt[c][k] = f2bf(W[i]);
    }
    if (tid < 128) { atts[tid] = att_src[tid]; attd[tid] = att_dst[tid]; }
    __syncthreads();

    const int w    = tid >> 6;
    const int lane = tid & 63;
    const int quad = lane >> 4;
    const int l15  = lane & 15;

    for (int base = blockIdx.x * 64; base < NODES; base += gridDim.x * 64) {
        const int arow = base + w * 16 + l15;
        short8 af[4];
        if (arow < NODES) {
            const float* xp = x + (size_t)arow * INC + quad * 8;
            #pragma unroll
            for (int kt = 0; kt < 4; ++kt) {
                float4 u = *(const float4*)(xp + kt * 32);
                float4 v = *(const float4*)(xp + kt * 32 + 4);
                short8 a;
                a[0] = (short)f2bf(u.x); a[1] = (short)f2bf(u.y);
                a[2] = (short)f2bf(u.z); a[3] = (short)f2bf(u.w);
                a[4] = (short)f2bf(v.x); a[5] = (short)f2bf(v.y);
                a[6] = (short)f2bf(v.z); a[7] = (short)f2bf(v.w);
                af[kt] = a;
            }
        } else {
            #pragma unroll
            for (int kt = 0; kt < 4; ++kt) af[kt] = (short8){0,0,0,0,0,0,0,0};
        }

        f32x4 accs[8];
        #pragma unroll
        for (int ct = 0; ct < 8; ++ct) {
            const int gcol = ct * 16 + l15;
            f32x4 acc = {0.f, 0.f, 0.f, 0.f};
            #pragma unroll
            for (int kt = 0; kt < 4; ++kt) {
                short8 bf = *(short8*)(&Wt[gcol][kt * 32 + quad * 8]);
                acc = __builtin_amdgcn_mfma_f32_16x16x32_bf16(af[kt], bf, acc, 0, 0, 0);
            }
            accs[ct] = acc;
        }

        const int orow = base + w * 16 + quad * 4;   // + reg

        #pragma unroll
        for (int head = 0; head < HH; ++head) {
            const float asl = atts[head * 32 + l15], ash = atts[head * 32 + 16 + l15];
            const float adl = attd[head * 32 + l15], adh = attd[head * 32 + 16 + l15];
            #pragma unroll
            for (int reg = 0; reg < 4; ++reg) {
                float ps = accs[head * 2][reg] * asl + accs[head * 2 + 1][reg] * ash;
                float pd = accs[head * 2][reg] * adl + accs[head * 2 + 1][reg] * adh;
                ps += __shfl_xor(ps, 1, 16); ps += __shfl_xor(ps, 2, 16);
                ps += __shfl_xor(ps, 4, 16); ps += __shfl_xor(ps, 8, 16);
                pd += __shfl_xor(pd, 1, 16); pd += __shfl_xor(pd, 2, 16);
                pd += __shfl_xor(pd, 4, 16); pd += __shfl_xor(pd, 8, 16);
                int r = orow + reg;
                if (l15 == 0 && r < NODES) {
                    a_src[r * HH + head] = ps;
                    a_dst[r * HH + head] = pd;
                }
            }
        }

        #pragma unroll
        for (int reg = 0; reg < 4; ++reg) {
            int r = orow + reg;
            if (r < NODES) {
                ushort4 lo, hi;
                lo.x = f2bf(accs[0][reg]); lo.y = f2bf(accs[2][reg]);
                lo.z = f2bf(accs[4][reg]); lo.w = f2bf(accs[6][reg]);
                hi.x = f2bf(accs[1][reg]); hi.y = f2bf(accs[3][reg]);
                hi.z = f2bf(accs[5][reg]); hi.w = f2bf(accs[7][reg]);
                *(ushort4*)(hb + (size_t)r * INC + l15 * 4) = lo;
                *(ushort4*)(hb + (size_t)r * INC + (16 + l15) * 4) = hi;
            }
        }
    }
}

// K2: thread-per-(edge,head); 4 consecutive lanes -> one coalesced 16B atomic.
// Also caches p = exp(leaky(logit)) as bf16 for the scatter pass.
__global__ void k_denom(const int* __restrict__ ei, const float* __restrict__ a_src,
        const float* __restrict__ a_dst, float* __restrict__ denom,
        unsigned short* __restrict__ pe) {
    int idx = blockIdx.x * blockDim.x + threadIdx.x;
    if (idx >= ET * HH) return;
    int e = idx >> 2, hh = idx & 3;
    int s, d;
    if (e < NEDGE) { s = ei[e]; d = ei[NEDGE + e]; } else { s = d = e - NEDGE; }
    float v = a_src[s * HH + hh] + a_dst[d * HH + hh];
    v = v > 0.f ? v : NEG * v;
    float p = __expf(v);
    atomicAdd(&denom[d * HH + hh], p);
    pe[idx] = f2bf(p);
}

// K3: 16 lanes per edge; lane l owns cols {2l, 2l+1}. Lanes 0-3 read cached
// p (coalesced) + denom (one random 16B), divide, broadcast (width-16 shfl).
// Lane l loads all 8 bf16 (2 cols x 4 heads) in ONE 16B load, combines in
// fp32, and issues ONE packed-fp16 dword atomic (2 accumulators/dword):
// 16 dword-atomics per edge instead of 32 -> halves the atomic-ALU floor.
__global__ __launch_bounds__(256) void k_scatter(const int* __restrict__ ei,
        const unsigned short* __restrict__ pe, const float* __restrict__ denom,
        const unsigned short* __restrict__ hb, unsigned short* __restrict__ acch) {
    int gt = blockIdx.x * 256 + threadIdx.x;
    int e = gt >> 4;
    int l = threadIdx.x & 15;
    if (e >= ET) return;
    int s, d;
    if (e < NEDGE) { s = ei[e]; d = ei[NEDGE + e]; } else { s = d = e - NEDGE; }

    float al = 0.f;
    if (l < 4) {
        float p = bf2f(pe[e * 4 + l]);
        al = p / (denom[d * HH + l] + 1e-16f);
    }
    float al0 = __shfl(al, 0, 16);
    float al1 = __shfl(al, 1, 16);
    float al2 = __shfl(al, 2, 16);
    float al3 = __shfl(al, 3, 16);

    u16x8 hv = *(const u16x8*)(hb + (size_t)s * INC + l * 8);   // 16B
    float v0 = al0 * bf2f(hv[0]) + al1 * bf2f(hv[1])
             + al2 * bf2f(hv[2]) + al3 * bf2f(hv[3]);
    float v1 = al0 * bf2f(hv[4]) + al1 * bf2f(hv[5])
             + al2 * bf2f(hv[6]) + al3 * bf2f(hv[7]);
    pk_add_f16(acch + (size_t)d * CC + l * 2, 0.25f * v0, 0.25f * v1);
}

// K4: out = relu(fp16 acc + bias)
__global__ void k_final(const unsigned short* __restrict__ acch,
        const float* __restrict__ bias, float* __restrict__ out) {
    int i = blockIdx.x * blockDim.x + threadIdx.x;
    if (i >= NODES * CC) return;
    _Float16 hbits = *(const _Float16*)(acch + i);
    float v = (float)hbits + bias[i & (CC - 1)];
    out[i] = v > 0.f ? v : 0.f;
}

extern "C" void kernel_launch(void* const* d_in, const int* in_sizes, int n_in,
                              void* d_out, int out_size, void* d_ws, size_t ws_size,
                              hipStream_t stream) {
    const float* x       = (const float*)d_in[0];
    const int*   ei      = (const int*)d_in[1];
    const float* W       = (const float*)d_in[2];
    const float* att_src = (const float*)d_in[3];
    const float* att_dst = (const float*)d_in[4];
    const float* bias    = (const float*)d_in[5];
    float* out = (float*)d_out;

    unsigned short* hb = (unsigned short*)d_ws;              // N*128 bf16 = 25.6 MB
    unsigned short* pe = hb + (size_t)NODES * INC;           // ET*4 bf16 = 13.6 MB
    float* fbase  = (float*)(pe + (size_t)ET * HH);
    float* a_src  = fbase;                                   // N*4 f32
    float* a_dst  = a_src + (size_t)NODES * HH;              // N*4 f32
    float* denom  = a_dst + (size_t)NODES * HH;              // N*4 f32
    unsigned short* acch = (unsigned short*)(denom + (size_t)NODES * HH);  // N*32 fp16
    // zero denom (f32) + acch (fp16) in one contiguous memset
    hipMemsetAsync(denom, 0,
                   (size_t)NODES * HH * 4 + (size_t)NODES * CC * 2, stream);

    k_proj<<<521, 256, 0, stream>>>(x, W, att_src, att_dst, hb, a_src, a_dst);

    k_denom<<<(ET * HH + 255) / 256, 256, 0, stream>>>(ei, a_src, a_dst, denom, pe);

    long long t3 = (long long)ET * 16;
    k_scatter<<<(int)((t3 + 255) / 256), 256, 0, stream>>>(ei, pe, denom, hb, acch);

    k_final<<<(NODES * CC + 255) / 256, 256, 0, stream>>>(acch, bias, out);
}